// Round 3
// baseline (463.036 us; speedup 1.0000x reference)
//
#include <hip/hip_runtime.h>
#include <stdint.h>

typedef float f32x16 __attribute__((ext_vector_type(16)));
typedef short bf16x8 __attribute__((ext_vector_type(8)));
typedef uint32_t u32;

#define T_LEN 8192
#define E_DIM 64
#define WSZ   128
#define NWIN  64
#define NBH   32
#define SCALE 0.125f

union Frag { u32 w[4]; bf16x8 v; };

__device__ __forceinline__ u32 pkbf(float a, float b) {
    u32 r;
    asm("v_cvt_pk_bf16_f32 %0, %1, %2" : "=v"(r) : "v"(a), "v"(b));
    return r;
}

// bf16 [128 keys][64 e] tile, row = 128B, XOR-swizzled (bijective; same fn for
// read and write). Proven 0-conflict for uint2 staging writes + b128 row reads
// (rounds 1-2); u16 column reads land 32 lanes in a permuted 64B window = 2-way.
__device__ __forceinline__ u32 swz(u32 key, u32 bir) {
    return (key * 128u + bir) ^ ((key & 15u) << 4);
}

__global__ __launch_bounds__(256, 4)
void lattn_kernel(const float* __restrict__ qg, const float* __restrict__ kg,
                  const float* __restrict__ vg, float* __restrict__ outg) {
    __shared__ __align__(16) char lds[32768];  // [0,16K): K half-tile, [16K,32K): V half-tile

    const int tid  = threadIdx.x;
    const int lane = tid & 63;
    const int wid  = tid >> 6;   // wave 0..3, owns queries [wid*32, wid*32+32)
    const int h    = lane >> 5;
    const int ql   = lane & 31;

    // XCD-contiguous window mapping
    const int bid = blockIdx.x;
    const int sw  = ((bid & 7) << 8) | (bid >> 3);
    const int bh  = sw >> 6;
    const int w   = sw & 63;

    const size_t qrow0 = (size_t)bh * T_LEN + (size_t)w * WSZ;
    const long   krow0 = (long)bh * T_LEN + (long)(w - 1) * WSZ;  // row of key 0

    // ---- Q fragments (B operand of S^T = K*Q^T), pre-scaled ----
    Frag qf[4];
    {
        const float* qp = qg + (qrow0 + (size_t)(wid * 32 + ql)) * E_DIM;
#pragma unroll
        for (int ks = 0; ks < 4; ++ks) {
            float4 x = *(const float4*)(qp + ks * 16 + h * 8);
            float4 y = *(const float4*)(qp + ks * 16 + h * 8 + 4);
            qf[ks].w[0] = pkbf(x.x * SCALE, x.y * SCALE);
            qf[ks].w[1] = pkbf(x.z * SCALE, x.w * SCALE);
            qf[ks].w[2] = pkbf(y.x * SCALE, y.y * SCALE);
            qf[ks].w[3] = pkbf(y.z * SCALE, y.w * SCALE);
        }
    }

    f32x16 o0, o1;
#pragma unroll
    for (int r = 0; r < 16; ++r) { o0[r] = 0.f; o1[r] = 0.f; }
    float den = 0.f;
    const int qpos = wid * 32 + ql;

    const int kb0 = (w == 0) ? 1 : 0;   // w==0: previous window absent, skip it
    for (int kb = kb0; kb < 2; ++kb) {
        __syncthreads();   // previous half's LDS reads done
        // ---- stage K+V half: 128 keys x 64 e, f32->bf16, coalesced float4 ----
        {
            const long rb = krow0 + (long)kb * 128;
#pragma unroll
            for (int i = 0; i < 8; ++i) {
                const int f = i * 256 + tid;
                const int row = f >> 4, c = f & 15;
                const size_t off = (size_t)(rb + row) * E_DIM + 4 * c;
                const float4 kv = *(const float4*)(kg + off);
                const float4 vv = *(const float4*)(vg + off);
                *(uint2*)(lds + swz((u32)row, 8u * c)) =
                    make_uint2(pkbf(kv.x, kv.y), pkbf(kv.z, kv.w));
                *(uint2*)(lds + 16384 + swz((u32)row, 8u * c)) =
                    make_uint2(pkbf(vv.x, vv.y), pkbf(vv.z, vv.w));
            }
        }
        __syncthreads();

        const bool MASK = (kb == 1);   // kb==0 keys are all in the past: no mask
#pragma unroll
        for (int b = 0; b < 4; ++b) {
            // ---- S^T = K * Q^T for 32 keys ----
            f32x16 a;
#pragma unroll
            for (int r = 0; r < 16; ++r) a[r] = 0.f;
#pragma unroll
            for (int ks = 0; ks < 4; ++ks) {
                const bf16x8 kf = *(const bf16x8*)(lds + swz((u32)(32 * b + ql),
                                                             (u32)(32 * ks + 16 * h)));
                a = __builtin_amdgcn_mfma_f32_32x32x16_bf16(kf, qf[ks].v, a, 0, 0, 0);
            }
            // ---- exp (+ causal mask only in current window) ----
#pragma unroll
            for (int r = 0; r < 16; ++r) {
                float p = __expf(a[r]);
                if (MASK) {
                    const int kr = 32 * b + 4 * h + (r & 3) + 8 * (r >> 2);
                    p = (kr <= qpos) ? p : 0.f;
                }
                a[r] = p;
                den += p;
            }
            // ---- pack P -> bf16 A-operand (lane^32 exchange), PV from LDS ----
            u32 W[8];
#pragma unroll
            for (int j = 0; j < 8; ++j) W[j] = pkbf(a[2 * j], a[2 * j + 1]);
#pragma unroll
            for (int hi = 0; hi < 2; ++hi) {
                const u32 w0 = W[4 * hi + 0], w1 = W[4 * hi + 1];
                const u32 w2 = W[4 * hi + 2], w3 = W[4 * hi + 3];
                const u32 y0 = (u32)__shfl_xor((int)w0, 32);
                const u32 y1 = (u32)__shfl_xor((int)w1, 32);
                const u32 y2 = (u32)__shfl_xor((int)w2, 32);
                const u32 y3 = (u32)__shfl_xor((int)w3, 32);
                Frag au;
                au.w[0] = h ? y2 : w0;
                au.w[1] = h ? y3 : w1;
                au.w[2] = h ? w2 : y0;
                au.w[3] = h ? w3 : y1;
                const int k0 = 32 * b + 16 * hi + 8 * h;  // half-local key of B elem 0
                u32 t0[8], t1[8];
#pragma unroll
                for (int j = 0; j < 8; ++j) {
                    t0[j] = *(const uint16_t*)(lds + 16384 + swz((u32)(k0 + j), 2u * ql));
                    t1[j] = *(const uint16_t*)(lds + 16384 + swz((u32)(k0 + j), 2u * (ql + 32)));
                }
                Frag b0, b1;
#pragma unroll
                for (int j = 0; j < 4; ++j) {
                    b0.w[j] = t0[2 * j] | (t0[2 * j + 1] << 16);
                    b1.w[j] = t1[2 * j] | (t1[2 * j + 1] << 16);
                }
                o0 = __builtin_amdgcn_mfma_f32_32x32x16_bf16(au.v, b0.v, o0, 0, 0, 0);
                o1 = __builtin_amdgcn_mfma_f32_32x32x16_bf16(au.v, b1.v, o1, 0, 0, 0);
            }
        }
    }

    den += __shfl_xor(den, 32);
    const float invd = 1.f / den;

    // ---- normalize + store (row of D = query, col = d) ----
    float* ob = outg + (qrow0 + (size_t)(wid * 32)) * E_DIM;
#pragma unroll
    for (int r = 0; r < 16; ++r) {
        const int rowq = (r & 3) + 8 * (r >> 2) + 4 * h;
        const float dn = __shfl(invd, rowq);
        ob[(size_t)rowq * E_DIM + ql]      = o0[r] * dn;
        ob[(size_t)rowq * E_DIM + 32 + ql] = o1[r] * dn;
    }
}

extern "C" void kernel_launch(void* const* d_in, const int* in_sizes, int n_in,
                              void* d_out, int out_size, void* d_ws, size_t ws_size,
                              hipStream_t stream) {
    const float* q = (const float*)d_in[0];
    const float* k = (const float*)d_in[1];
    const float* v = (const float*)d_in[2];
    float* out = (float*)d_out;
    lattn_kernel<<<dim3(NBH * NWIN), dim3(256), 0, stream>>>(q, k, v, out);
}